// Round 9
// baseline (114.241 us; speedup 1.0000x reference)
//
#include <hip/hip_runtime.h>

#define B_SZ 16384
#define D_SZ 256
#define C_SZ 2000
#define C_PAD 2048
#define MARGIN_F 1.0f
#define NBLK 1024

typedef __bf16 bf16x8 __attribute__((ext_vector_type(8)));
typedef __bf16 bf16x4 __attribute__((ext_vector_type(4)));
typedef float floatx16 __attribute__((ext_vector_type(16)));

__device__ inline void gld_lds16(const void* g, void* l) {
  __builtin_amdgcn_global_load_lds(
      (const __attribute__((address_space(1))) void*)g,
      (__attribute__((address_space(3))) void*)l, 16, 0, 0);
}

// Frag-major layout for mfma_f32_32x32x16_bf16 (verified R3/R6-R8):
//   chunk(tile32, ks, lane) -> 8 bf16 at base + ((tile*16 + ks)*64 + lane)*8
//   lane holds M[tile*32 + (lane&31)][ks*16 + (lane>>5)*8 + j], j=0..7

// ---- kernel 1: sig (D x C) fp32 -> sigf frag-major bf16; zero done-counter ----
__global__ __launch_bounds__(256) void sigf_kernel(
    const float* __restrict__ sig, __bf16* __restrict__ sigf,
    unsigned int* __restrict__ cnt) {
  if (blockIdx.x == 0 && threadIdx.x == 0) *cnt = 0u;
  int ct = (int)blockIdx.x;             // coltile 0..63
#pragma unroll
  for (int it = 0; it < 4; it++) {
    int ch = it * 256 + threadIdx.x;
    int lane = ch & 63, ks = ch >> 6;
    int col = ct * 32 + (lane & 31);
    int kb = ks * 16 + (lane >> 5) * 8;
    bf16x8 o;
    if (col < C_SZ) {
#pragma unroll
      for (int j = 0; j < 8; j++) o[j] = (__bf16)sig[(size_t)(kb + j) * C_SZ + col];
    } else {
#pragma unroll
      for (int j = 0; j < 8; j++) o[j] = (__bf16)0.f;
    }
    *(bf16x8*)(sigf + ((size_t)(ct * 16 + ks) * 64 + lane) * 8) = o;
  }
}

// ---- kernel 2: prep — pred -> LDS -> predf (frag-major), gt (bf16-consistent) ----
// gt[b] = fp32 dot of bf16-rounded pred[b] and bf16 sigf[:,label_b]; the GEMM
// epilogue uses this gt, so the label column's hinge == MARGIN + O(1e-3),
// removed by subtracting B_SZ*MARGIN at the end. No mask, no corr.
__global__ __launch_bounds__(256) void prep_kernel(
    const float* __restrict__ pred, const __bf16* __restrict__ sigf,
    const int* __restrict__ label, __bf16* __restrict__ predf,
    float* __restrict__ gt) {
  __shared__ float ldsP[32][257];   // +1 pad: 2-way max on reads (free)
  int bid = (int)blockIdx.x;
  int tid = threadIdx.x;
  // phase A: coalesced tile load (32 rows x 256 cols fp32)
#pragma unroll
  for (int it = 0; it < 8; it++) {
    int idx = it * 1024 + tid * 4;
    int r = idx >> 8, c = idx & 255;
    float4 v = *(const float4*)(pred + (size_t)(bid * 32 + r) * D_SZ + c);
    ldsP[r][c] = v.x; ldsP[r][c + 1] = v.y;
    ldsP[r][c + 2] = v.z; ldsP[r][c + 3] = v.w;
  }
  __syncthreads();
  // phase B: frag-major predf, coalesced 16B/lane writes
#pragma unroll
  for (int it = 0; it < 4; it++) {
    int ch = it * 256 + tid;          // 0..1023
    int lane = ch & 63, ks = ch >> 6; // ks 0..15
    int r = lane & 31, kb = ks * 16 + (lane >> 5) * 8;
    bf16x8 o;
#pragma unroll
    for (int j = 0; j < 8; j++) o[j] = (__bf16)ldsP[r][kb + j];
    *(bf16x8*)(predf + ((size_t)(bid * 16 + ks) * 64 + lane) * 8) = o;
  }
  // phase C: gt, 4 waves x 8 rows; label column read from sigf (8B/lane)
  int lane = tid & 63, w = tid >> 6;
  for (int rr = 0; rr < 8; rr++) {
    int r = w * 8 + rr;
    int row = bid * 32 + r;
    int lbl = label[row];
    int tile = lbl >> 5, l5 = lbl & 31;
    int k0 = lane * 4;
    int ks = k0 >> 4;
    int kh = (k0 >> 3) & 1;
    int j0 = k0 & 7;                  // 0 or 4
    bf16x4 sb = *(const bf16x4*)(sigf +
        (((size_t)(tile * 16 + ks) * 64) + kh * 32 + l5) * 8 + j0);
    float s = 0.f;
#pragma unroll
    for (int i = 0; i < 4; i++)
      s += (float)(__bf16)ldsP[r][k0 + i] * (float)sb[i];
#pragma unroll
    for (int off = 32; off > 0; off >>= 1) s += __shfl_down(s, off, 64);
    if (lane == 0) gt[row] = s;
  }
}

// ---- kernel 3: GEMM + hinge + last-block final reduce ----
// block = 256 rows x 128 cols, 4 waves; wave = 64 rows (2 rowtiles) x 128.
// B in LDS once (1 barrier), full-K A in registers; 2 MFMAs per ds_read_b128.
__global__ __launch_bounds__(256, 2) void mfma_fused_kernel(
    const __bf16* __restrict__ predf, const __bf16* __restrict__ sigf,
    const float* __restrict__ gt, float* __restrict__ partial,
    unsigned int* __restrict__ cnt, float* __restrict__ out) {
  __shared__ __bf16 Bs[4096 * 8];   // 64 KB
  __shared__ float red[4];
  __shared__ float lastFlag;
  int tid = threadIdx.x;
  int lane = tid & 63;
  int w = tid >> 6;
  int kh = lane >> 5, lm = lane & 31;
  int bid = (int)blockIdx.x;
  int i = bid >> 3;
  int rsb = (bid & 7) * 8 + (i & 7);   // row superblock 0..63 (256 rows)
  int cg = i >> 3;                     // colgroup 0..15 (128 cols)

  // stage B tile (128 cols x 256 K = 64 KB), straight frag-major copy
#pragma unroll
  for (int s = 0; s < 16; s++) {
    int q0 = s * 256 + w * 64;
    gld_lds16(sigf + ((size_t)cg * 4096 + q0 + lane) * 8, (void*)(Bs + (size_t)q0 * 8));
  }

  // A frags: full K for 2 rowtiles (rows rsb*256 + w*64 .. +63)
  bf16x8 afr[2][16];
#pragma unroll
  for (int rt = 0; rt < 2; rt++)
#pragma unroll
    for (int ks = 0; ks < 16; ks++)
      afr[rt][ks] = *(const bf16x8*)(predf +
          (((size_t)(rsb * 8 + w * 2 + rt) * 16 + ks) * 64 + lane) * 8);

  // mg = margin - gt for the rows this lane owns (C/D row map, verified R3)
  float mgv[2][16];
#pragma unroll
  for (int rt = 0; rt < 2; rt++)
#pragma unroll
    for (int reg = 0; reg < 16; reg++) {
      int row = rsb * 256 + w * 64 + rt * 32 + (reg & 3) + 8 * (reg >> 2) + 4 * kh;
      mgv[rt][reg] = MARGIN_F - gt[row];
    }
  __syncthreads();

  float sum = 0.f;
  for (int ct = 0; ct < 4; ct++) {
    floatx16 acc0 = {}, acc1 = {};
#pragma unroll
    for (int ks = 0; ks < 16; ks++) {
      bf16x8 bfr = *(const bf16x8*)(Bs + (size_t)((ct * 16 + ks) * 64 + lane) * 8);
      acc0 = __builtin_amdgcn_mfma_f32_32x32x16_bf16(afr[0][ks], bfr, acc0, 0, 0, 0);
      acc1 = __builtin_amdgcn_mfma_f32_32x32x16_bf16(afr[1][ks], bfr, acc1, 0, 0, 0);
    }
    int col = cg * 128 + ct * 32 + lm;
    float keep = (col < C_SZ) ? 1.f : 0.f;   // zero-padded cols give s=0 but hinge!=0
#pragma unroll
    for (int reg = 0; reg < 16; reg++) {
      sum += keep * fmaxf(acc0[reg] + mgv[0][reg], 0.f);
      sum += keep * fmaxf(acc1[reg] + mgv[1][reg], 0.f);
    }
  }
#pragma unroll
  for (int off = 32; off > 0; off >>= 1) sum += __shfl_down(sum, off, 64);
  if (lane == 0) red[w] = sum;
  __syncthreads();
  if (tid == 0) {
    partial[bid] = red[0] + red[1] + red[2] + red[3];
    __threadfence();                          // make partial visible device-wide
    unsigned int old = atomicAdd(cnt, 1u);
    lastFlag = (old == NBLK - 1) ? 1.f : 0.f;
  }
  __syncthreads();
  if (lastFlag != 0.f) {
    // last block: total = sum(partial) - B*MARGIN (label-column hinges)
    float s = (tid == 0) ? -(float)B_SZ * MARGIN_F : 0.f;
    for (int p = tid; p < NBLK; p += 256)
      s += atomicAdd(&partial[p], 0.f);       // coherent read across XCDs
#pragma unroll
    for (int off = 32; off > 0; off >>= 1) s += __shfl_down(s, off, 64);
    if (lane == 0) red[w] = s;
    __syncthreads();
    if (tid == 0) out[0] = red[0] + red[1] + red[2] + red[3];
  }
}

extern "C" void kernel_launch(void* const* d_in, const int* in_sizes, int n_in,
                              void* d_out, int out_size, void* d_ws, size_t ws_size,
                              hipStream_t stream) {
  const float* pred  = (const float*)d_in[0];   // (B, D) fp32
  const int*   label = (const int*)d_in[1];     // (B,)
  // d_in[2] = train_classes = arange(C), unused
  const float* sig   = (const float*)d_in[3];   // (D, C) fp32
  float* out = (float*)d_out;

  float*        gt      = (float*)d_ws;                               // 64 KB
  float*        partial = (float*)((char*)d_ws + (64 << 10));         // 4 KB
  unsigned int* cnt     = (unsigned int*)((char*)d_ws + (68 << 10));  // 4 B
  __bf16*       predf   = (__bf16*)((char*)d_ws + (128 << 10));       // 8 MB
  __bf16*       sigf    = (__bf16*)((char*)d_ws + (128 << 10) + (8 << 20)); // 1 MB

  sigf_kernel<<<64, 256, 0, stream>>>(sig, sigf, cnt);
  prep_kernel<<<512, 256, 0, stream>>>(pred, sigf, label, predf, gt);
  mfma_fused_kernel<<<NBLK, 256, 0, stream>>>(predf, sigf, gt, partial, cnt, out);
}